// Round 1
// baseline (39.395 us; speedup 1.0000x reference)
//
#include <hip/hip_runtime.h>

#define MARGIN 0.1f
#define EPSF   1e-12f
#define BB 32
#define NN 2048
#define DD 128

// Kernel 1: dist[b][n] for all rows. 32-lane group per row, float4 loads.
__global__ __launch_bounds__(256) void dist_kernel(const float* __restrict__ anchors,
                                                   const float* __restrict__ feats,
                                                   float* __restrict__ dist) {
    const int chunk = blockIdx.x;   // 0..31 (64 rows each)
    const int b     = blockIdx.y;   // 0..31
    const int t     = threadIdx.x;
    const int g     = t >> 5;       // group 0..7
    const int sub   = t & 31;       // lane within group

    // anchor fragment (4 floats per lane covers D=128 across 32 lanes)
    const float4 a4 = ((const float4*)(anchors + b * DD))[sub];
    float a2 = a4.x*a4.x + a4.y*a4.y + a4.z*a4.z + a4.w*a4.w;
    #pragma unroll
    for (int m = 16; m >= 1; m >>= 1) a2 += __shfl_xor(a2, m);
    const float ra    = sqrtf(a2);
    const float inva  = 1.0f / (ra + EPSF);
    const float s_anc = (ra * inva) * (ra * inva);

    const float* fp = feats + ((size_t)b * NN) * DD;
    #pragma unroll
    for (int it = 0; it < 8; ++it) {
        const int n = chunk * 64 + it * 8 + g;
        const float4 f4 = ((const float4*)(fp + (size_t)n * DD))[sub];
        float ss = f4.x*f4.x + f4.y*f4.y + f4.z*f4.z + f4.w*f4.w;
        float dt = a4.x*f4.x + a4.y*f4.y + a4.z*f4.z + a4.w*f4.w;
        #pragma unroll
        for (int m = 16; m >= 1; m >>= 1) {
            ss += __shfl_xor(ss, m);
            dt += __shfl_xor(dt, m);
        }
        const float rf   = sqrtf(ss);
        const float invf = 1.0f / (rf + EPSF);
        const float sq   = s_anc + (rf*invf)*(rf*invf) - 2.0f * dt * inva * invf;
        const float dd   = sqrtf(fmaxf(sq, 1e-12f));
        if (sub == 0) dist[b * NN + n] = dd;
    }
}

// Kernel 2: pair loss. Block = (chunk of 256 i-rows) x batch. LDS holds
// per-j "effective negative distance" (1e30 for non-negatives -> relu==0).
__global__ __launch_bounds__(256) void pair_kernel(const float* __restrict__ dist,
                                                   const int* __restrict__ tgt,
                                                   float* __restrict__ out) {
    __shared__ float sd[NN];
    __shared__ int   scnt[256];
    __shared__ float sred[4];

    const int chunk = blockIdx.x;   // 0..7
    const int b     = blockIdx.y;   // 0..31
    const int t     = threadIdx.x;

    const float* db = dist + b * NN;
    const int*   tb = tgt  + b * NN;

    // load dist + flags, build eff-neg array, count pos/neg (packed 16+16)
    int cnt = 0;
    #pragma unroll
    for (int k = 0; k < NN / 256; ++k) {
        const int j  = t + k * 256;
        const int tv = tb[j];
        const float dv = db[j];
        const bool neg = (tv == 0);
        const bool pos = (tv > 0);
        sd[j] = neg ? dv : 1e30f;
        cnt += (pos ? (1 << 16) : 0) + (neg ? 1 : 0);
    }
    scnt[t] = cnt;
    __syncthreads();
    #pragma unroll
    for (int s = 128; s >= 1; s >>= 1) {
        if (t < s) scnt[t] += scnt[t + s];
        __syncthreads();
    }
    const int n_pos = scnt[0] >> 16;
    const int n_neg = scnt[0] & 0xffff;

    // each thread owns one candidate-positive row i
    const int   i    = chunk * 256 + t;
    const float di   = db[i];
    const bool  posi = (tb[i] > 0);
    const float dim  = di + MARGIN;

    float acc0 = 0.f, acc1 = 0.f, acc2 = 0.f, acc3 = 0.f;
    const float4* s4 = (const float4*)sd;
    #pragma unroll 4
    for (int jj = 0; jj < NN / 4; ++jj) {
        const float4 q = s4[jj];           // broadcast ds_read_b128
        acc0 += fmaxf(dim - q.x, 0.0f);
        acc1 += fmaxf(dim - q.y, 0.0f);
        acc2 += fmaxf(dim - q.z, 0.0f);
        acc3 += fmaxf(dim - q.w, 0.0f);
    }
    float acc = posi ? ((acc0 + acc1) + (acc2 + acc3)) : 0.0f;

    // wave64 reduce, then cross-wave via LDS
    #pragma unroll
    for (int m = 32; m >= 1; m >>= 1) acc += __shfl_xor(acc, m);
    const int wid = t >> 6;
    if ((t & 63) == 0) sred[wid] = acc;
    __syncthreads();
    if (t == 0) {
        const float bsum  = (sred[0] + sred[1]) + (sred[2] + sred[3]);
        const float denom = fmaxf((float)n_pos * (float)n_neg, 1.0f);
        float val = bsum / denom;
        if (chunk == 0 && n_pos == 0) val += MARGIN;   // reference fallback
        atomicAdd(out, val);
    }
}

extern "C" void kernel_launch(void* const* d_in, const int* in_sizes, int n_in,
                              void* d_out, int out_size, void* d_ws, size_t ws_size,
                              hipStream_t stream) {
    const float* anchors = (const float*)d_in[0];
    const float* feats   = (const float*)d_in[1];
    const int*   tgt     = (const int*)d_in[2];
    float*       out     = (float*)d_out;
    float*       dist    = (float*)d_ws;   // B*N floats = 256 KB

    hipMemsetAsync(out, 0, sizeof(float), stream);
    dist_kernel<<<dim3(32, 32), 256, 0, stream>>>(anchors, feats, dist);
    pair_kernel<<<dim3(8, 32), 256, 0, stream>>>(dist, tgt, out);
}

// Round 2
// 34.692 us; speedup vs baseline: 1.1356x; 1.1356x over previous
//
#include <hip/hip_runtime.h>

#define MARGIN 0.1f
#define EPSF   1e-12f
#define BB 32
#define NN 2048
#define DD 128

// Kernel 1: dist[b][n] for all rows. 32-lane group per row, float4 loads.
// Also zeroes out[0] (replaces a separate memset dispatch).
__global__ __launch_bounds__(256) void dist_kernel(const float* __restrict__ anchors,
                                                   const float* __restrict__ feats,
                                                   float* __restrict__ dist,
                                                   float* __restrict__ out) {
    const int chunk = blockIdx.x;   // 0..31 (64 rows each)
    const int b     = blockIdx.y;   // 0..31
    const int t     = threadIdx.x;
    const int g     = t >> 5;       // group 0..7
    const int sub   = t & 31;       // lane within group

    if (chunk == 0 && b == 0 && t == 0) out[0] = 0.0f;

    // anchor fragment (4 floats per lane covers D=128 across 32 lanes)
    const float4 a4 = ((const float4*)(anchors + b * DD))[sub];
    float a2 = a4.x*a4.x + a4.y*a4.y + a4.z*a4.z + a4.w*a4.w;
    #pragma unroll
    for (int m = 16; m >= 1; m >>= 1) a2 += __shfl_xor(a2, m);
    const float ra    = sqrtf(a2);
    const float inva  = 1.0f / (ra + EPSF);
    const float s_anc = (ra * inva) * (ra * inva);

    const float* fp = feats + ((size_t)b * NN) * DD;
    #pragma unroll
    for (int it = 0; it < 8; ++it) {
        const int n = chunk * 64 + it * 8 + g;
        const float4 f4 = ((const float4*)(fp + (size_t)n * DD))[sub];
        float ss = f4.x*f4.x + f4.y*f4.y + f4.z*f4.z + f4.w*f4.w;
        float dt = a4.x*f4.x + a4.y*f4.y + a4.z*f4.z + a4.w*f4.w;
        #pragma unroll
        for (int m = 16; m >= 1; m >>= 1) {
            ss += __shfl_xor(ss, m);
            dt += __shfl_xor(dt, m);
        }
        const float rf   = sqrtf(ss);
        const float invf = 1.0f / (rf + EPSF);
        const float sq   = s_anc + (rf*invf)*(rf*invf) - 2.0f * dt * inva * invf;
        const float dd   = sqrtf(fmaxf(sq, 1e-12f));
        if (sub == 0) dist[b * NN + n] = dd;
    }
}

// Kernel 2: pair loss. Block = (chunk of 256 i-rows) x batch. LDS holds
// per-j "effective negative distance" (1e30 for non-negatives -> relu==0).
__global__ __launch_bounds__(256) void pair_kernel(const float* __restrict__ dist,
                                                   const int* __restrict__ tgt,
                                                   float* __restrict__ out) {
    __shared__ float sd[NN];
    __shared__ int   scnt[256];
    __shared__ float sred[4];

    const int chunk = blockIdx.x;   // 0..7
    const int b     = blockIdx.y;   // 0..31
    const int t     = threadIdx.x;

    const float* db = dist + b * NN;
    const int*   tb = tgt  + b * NN;

    // load dist + flags, build eff-neg array, count pos/neg (packed 16+16)
    int cnt = 0;
    #pragma unroll
    for (int k = 0; k < NN / 256; ++k) {
        const int j  = t + k * 256;
        const int tv = tb[j];
        const float dv = db[j];
        const bool neg = (tv == 0);
        const bool pos = (tv > 0);
        sd[j] = neg ? dv : 1e30f;
        cnt += (pos ? (1 << 16) : 0) + (neg ? 1 : 0);
    }
    scnt[t] = cnt;
    __syncthreads();
    #pragma unroll
    for (int s = 128; s >= 1; s >>= 1) {
        if (t < s) scnt[t] += scnt[t + s];
        __syncthreads();
    }
    const int n_pos = scnt[0] >> 16;
    const int n_neg = scnt[0] & 0xffff;

    // each thread owns one candidate-positive row i
    const int   i    = chunk * 256 + t;
    const float di   = db[i];
    const bool  posi = (tb[i] > 0);
    const float dim  = di + MARGIN;

    float acc0 = 0.f, acc1 = 0.f, acc2 = 0.f, acc3 = 0.f;
    const float4* s4 = (const float4*)sd;
    #pragma unroll 4
    for (int jj = 0; jj < NN / 4; ++jj) {
        const float4 q = s4[jj];           // broadcast ds_read_b128
        acc0 += fmaxf(dim - q.x, 0.0f);
        acc1 += fmaxf(dim - q.y, 0.0f);
        acc2 += fmaxf(dim - q.z, 0.0f);
        acc3 += fmaxf(dim - q.w, 0.0f);
    }
    float acc = posi ? ((acc0 + acc1) + (acc2 + acc3)) : 0.0f;

    // wave64 reduce, then cross-wave via LDS
    #pragma unroll
    for (int m = 32; m >= 1; m >>= 1) acc += __shfl_xor(acc, m);
    const int wid = t >> 6;
    if ((t & 63) == 0) sred[wid] = acc;
    __syncthreads();
    if (t == 0) {
        const float bsum  = (sred[0] + sred[1]) + (sred[2] + sred[3]);
        const float denom = fmaxf((float)n_pos * (float)n_neg, 1.0f);
        float val = bsum / denom;
        if (chunk == 0 && n_pos == 0) val += MARGIN;   // reference fallback
        atomicAdd(out, val);
    }
}

extern "C" void kernel_launch(void* const* d_in, const int* in_sizes, int n_in,
                              void* d_out, int out_size, void* d_ws, size_t ws_size,
                              hipStream_t stream) {
    const float* anchors = (const float*)d_in[0];
    const float* feats   = (const float*)d_in[1];
    const int*   tgt     = (const int*)d_in[2];
    float*       out     = (float*)d_out;
    float*       dist    = (float*)d_ws;   // B*N floats = 256 KB

    dist_kernel<<<dim3(32, 32), 256, 0, stream>>>(anchors, feats, dist, out);
    pair_kernel<<<dim3(8, 32), 256, 0, stream>>>(dist, tgt, out);
}

// Round 3
// 24.366 us; speedup vs baseline: 1.6168x; 1.4238x over previous
//
#include <hip/hip_runtime.h>

#define MARGIN 0.1f
#define EPSF   1e-12f
#define BB 32
#define NN 2048
#define DD 128
#define PAD 16   // partials stride in floats (64 B -> separate cache lines)

// ws layout: dist[B*NN] floats | partials[B*PAD] floats | counts[B*2] ints

// Kernel 1: dist[b][n]. 32-lane group per row, float4 loads.
// Block (0,0) also zeroes the partials cells (stream order protects pair's atomics).
__global__ __launch_bounds__(256) void dist_kernel(const float* __restrict__ anchors,
                                                   const float* __restrict__ feats,
                                                   float* __restrict__ dist,
                                                   float* __restrict__ partials) {
    const int chunk = blockIdx.x;   // 0..31 (64 rows each)
    const int b     = blockIdx.y;   // 0..31
    const int t     = threadIdx.x;
    const int g     = t >> 5;       // group 0..7
    const int sub   = t & 31;       // lane within group

    if (chunk == 0 && b == 0 && t < BB) partials[t * PAD] = 0.0f;

    const float4 a4 = ((const float4*)(anchors + b * DD))[sub];
    float a2 = a4.x*a4.x + a4.y*a4.y + a4.z*a4.z + a4.w*a4.w;
    #pragma unroll
    for (int m = 16; m >= 1; m >>= 1) a2 += __shfl_xor(a2, m);
    const float ra    = sqrtf(a2);
    const float inva  = 1.0f / (ra + EPSF);
    const float s_anc = (ra * inva) * (ra * inva);

    const float* fp = feats + ((size_t)b * NN) * DD;
    #pragma unroll
    for (int it = 0; it < 8; ++it) {
        const int n = chunk * 64 + it * 8 + g;
        const float4 f4 = ((const float4*)(fp + (size_t)n * DD))[sub];
        float ss = f4.x*f4.x + f4.y*f4.y + f4.z*f4.z + f4.w*f4.w;
        float dt = a4.x*f4.x + a4.y*f4.y + a4.z*f4.z + a4.w*f4.w;
        #pragma unroll
        for (int m = 16; m >= 1; m >>= 1) {
            ss += __shfl_xor(ss, m);
            dt += __shfl_xor(dt, m);
        }
        const float rf   = sqrtf(ss);
        const float invf = 1.0f / (rf + EPSF);
        const float sq   = s_anc + (rf*invf)*(rf*invf) - 2.0f * dt * inva * invf;
        const float dd   = sqrtf(fmaxf(sq, 1e-12f));
        if (sub == 0) dist[b * NN + n] = dd;
    }
}

// Kernel 2: compacted pair loss. Block = (64 i-rows) x b. Wave-ballot compaction:
// sd[] = compacted negative-j distances (full row), pd[] = compacted positive d_i
// of this block's 64-row range. Inner loop touches only real (pos,neg) pairs.
__global__ __launch_bounds__(256) void pair_kernel(const float* __restrict__ dist,
                                                   const int* __restrict__ tgt,
                                                   float* __restrict__ partials,
                                                   int* __restrict__ counts) {
    __shared__ float sd[NN + 4];
    __shared__ float pd[64];
    __shared__ int   negcnt, posglob, npblk;
    __shared__ float sred[4];

    const int chunk = blockIdx.x;   // 0..31
    const int b     = blockIdx.y;   // 0..31
    const int t     = threadIdx.x;
    const int lane  = t & 63;

    const float* db = dist + b * NN;
    const int*   tb = tgt  + b * NN;

    if (t == 0) { negcnt = 0; posglob = 0; }
    __syncthreads();

    // Compact negatives from the full row; count positives globally.
    #pragma unroll
    for (int k = 0; k < 8; ++k) {
        const int j  = k * 256 + t;
        const float dv = db[j];
        const int   tv = tb[j];
        const bool  neg = (tv == 0);
        const bool  pos = (tv > 0);
        const unsigned long long nm = __ballot(neg);
        const unsigned long long pm = __ballot(pos);
        int base;
        if (lane == 0) {
            base = atomicAdd(&negcnt, __popcll(nm));
            atomicAdd(&posglob, __popcll(pm));
        }
        base = __shfl(base, 0);
        if (neg) {
            const int off = __popcll(nm & ((1ull << lane) - 1));
            sd[base + off] = dv;
        }
    }
    // Compact this block's positive d_i (wave 0 handles the 64-row range).
    if (t < 64) {
        const int   i   = chunk * 64 + t;
        const float dv  = db[i];
        const bool  pos = (tb[i] > 0);
        const unsigned long long pm = __ballot(pos);
        if (pos) pd[__popcll(pm & ((1ull << t) - 1))] = dv;
        if (t == 0) npblk = __popcll(pm);
    }
    __syncthreads();

    const int nn     = negcnt;
    const int np     = posglob;
    const int npb    = npblk;
    const int nn_pad = (nn + 3) & ~3;
    if (t < nn_pad - nn) sd[nn + t] = 1e30f;   // sentinel pad -> relu 0
    __syncthreads();

    // Quad layout: 4 threads per positive slot, interleaved float4 j-stripes.
    float acc = 0.0f;
    const int p = t >> 2;
    if (p < npb) {
        const float  x   = pd[p] + MARGIN;
        const float4* s4 = (const float4*)sd;
        const int    nf4 = nn_pad >> 2;
        float a0 = 0.f, a1 = 0.f, a2 = 0.f, a3 = 0.f;
        #pragma unroll 4
        for (int f = (t & 3); f < nf4; f += 4) {
            const float4 q = s4[f];        // 4 distinct addrs/wave, banks 0-15: conflict-free
            a0 += fmaxf(x - q.x, 0.0f);
            a1 += fmaxf(x - q.y, 0.0f);
            a2 += fmaxf(x - q.z, 0.0f);
            a3 += fmaxf(x - q.w, 0.0f);
        }
        acc = (a0 + a1) + (a2 + a3);
    }

    #pragma unroll
    for (int m = 32; m >= 1; m >>= 1) acc += __shfl_xor(acc, m);
    if (lane == 0) sred[t >> 6] = acc;
    __syncthreads();
    if (t == 0) {
        const float bsum = (sred[0] + sred[1]) + (sred[2] + sred[3]);
        atomicAdd(&partials[b * PAD], bsum);          // 32 adds per cell, cells 64 B apart
        if (chunk == 0) { counts[b * 2] = np; counts[b * 2 + 1] = nn; }
    }
}

// Kernel 3: apply denom / fallback per b, sum, write out.
__global__ void final_kernel(const float* __restrict__ partials,
                             const int* __restrict__ counts,
                             float* __restrict__ out) {
    const int t = threadIdx.x;   // 64
    float v = 0.0f;
    if (t < BB) {
        const float rs = partials[t * PAD];
        const int   np = counts[t * 2];
        const int   nn = counts[t * 2 + 1];
        const float denom = fmaxf((float)np * (float)nn, 1.0f);
        v = (np > 0) ? rs / denom : MARGIN;
    }
    #pragma unroll
    for (int m = 32; m >= 1; m >>= 1) v += __shfl_xor(v, m);
    if (t == 0) out[0] = v;
}

extern "C" void kernel_launch(void* const* d_in, const int* in_sizes, int n_in,
                              void* d_out, int out_size, void* d_ws, size_t ws_size,
                              hipStream_t stream) {
    const float* anchors = (const float*)d_in[0];
    const float* feats   = (const float*)d_in[1];
    const int*   tgt     = (const int*)d_in[2];
    float*       out     = (float*)d_out;

    float* dist     = (float*)d_ws;                    // B*NN floats
    float* partials = dist + BB * NN;                  // B*PAD floats
    int*   counts   = (int*)(partials + BB * PAD);     // B*2 ints

    dist_kernel<<<dim3(32, 32), 256, 0, stream>>>(anchors, feats, dist, partials);
    pair_kernel<<<dim3(32, 32), 256, 0, stream>>>(dist, tgt, partials, counts);
    final_kernel<<<1, 64, 0, stream>>>(partials, counts, out);
}